// Round 12
// baseline (10643.421 us; speedup 1.0000x reference)
//
#include <hip/hip_runtime.h>
#include <math.h>

// LSTM: B=64, T=784, I=1, H=600.
// 200 WGs = 50 cell-groups x 4 batch-groups (r4-proven protocol), but the
// in-WG step is restructured as per-wave chunk dataflow:
//   - W_hh in LDS [48][612] (2-way bank reads = free)
//   - k split into 50 chunks of 12 (chunk == producer); wave w owns 6-7
//     chunks: polls its producers in parallel, stages via global_load_lds
//     (sc0|sc1) into private LDS buffers, drains with counted vmcnt.
//   - no barrier inside the GEMV phase; cross-wave reduce via LDS f32 atomics.
//   - 3 barriers/step; producer signal = 3 per-wave atomicAdds (threshold 3t).
#define BB 64
#define TT 784
#define HH 600
#define CG 50           // cell-groups == chunks
#define CPW 12          // cells per WG -> 48 gate-rows; also chunk k-width
#define BW 16           // batches per WG
#define NWG (CG*4)      // 200
#define BLOCK 512       // 8 waves
#define WSTR 612        // W_lds row stride (dwords): 12rt-mod-32 tiles banks
#define CBUF_DW 192     // per-chunk staging buffer: 48 lanes x 16 B
#define NBUF 7          // max chunks per wave
#define LDS_BYTES ((48*WSTR + 8*NBUF*CBUF_DW + 48*16)*4)   // 163,584 B

typedef float f2v __attribute__((ext_vector_type(2)));

__device__ __forceinline__ float sigm_f(float v) {
    return 1.f / (1.f + __expf(-v));
}
__device__ __forceinline__ float tanh_f(float v) {
    return 1.f - 2.f / (__expf(2.f * v) + 1.f);
}

__device__ __forceinline__ void stg_bypass(float* p, float v) {
    asm volatile("global_store_dword %0, %1, off sc0 sc1"
                 :: "v"(p), "v"(v) : "memory");
}

// process NCH staged chunks with counted-vmcnt drain (all loads already issued)
template<int NCH>
__device__ __forceinline__ void process_chunks(const float* __restrict__ W_lds,
                                               const float* __restrict__ mycbuf,
                                               int nst, int rt, int bt,
                                               f2v (&acc2)[3][4])
{
    #pragma unroll
    for (int i = 0; i < NCH; ++i) {
        asm volatile("s_waitcnt vmcnt(%c0)" :: "n"(NCH - 1 - i) : "memory");
        __builtin_amdgcn_sched_barrier(0);
        const float* cb = mycbuf + i * CBUF_DW;
        // h fragment: batches 4bt..4bt+3, 12 k of this chunk (3 f4 per batch)
        float4 hv[4][3];
        #pragma unroll
        for (int jj = 0; jj < 4; ++jj)
            #pragma unroll
            for (int jc = 0; jc < 3; ++jc)
                hv[jj][jc] = *(const float4*)&cb[(3 * (4 * bt + jj) + jc) * 4];
        const int p = nst + i;
        #pragma unroll
        for (int ii = 0; ii < 3; ++ii) {
            const float* wrow = W_lds + (3 * rt + ii) * WSTR + 12 * p;
            #pragma unroll
            for (int jc = 0; jc < 3; ++jc) {
                float4 wv = *(const float4*)&wrow[4 * jc];
                const f2v* w2 = (const f2v*)&wv;
                #pragma unroll
                for (int jj = 0; jj < 4; ++jj) {
                    const f2v* h2 = (const f2v*)&hv[jj][jc];
                    acc2[ii][jj] = __builtin_elementwise_fma(w2[0], h2[0], acc2[ii][jj]);
                    acc2[ii][jj] = __builtin_elementwise_fma(w2[1], h2[1], acc2[ii][jj]);
                }
            }
        }
    }
}

extern "C" __global__ void __launch_bounds__(BLOCK)
lstm_main(const float* __restrict__ x, const float* __restrict__ hs0,
          const float* __restrict__ cs0, const float* __restrict__ W_ih,
          const float* __restrict__ W_hh, const float* __restrict__ b_ih,
          const float* __restrict__ b_hh, float* __restrict__ hbuf,
          unsigned int* __restrict__ flags)
{
    extern __shared__ float lds[];
    float* W_lds = lds;                                  // [48][612]
    float* cbuf  = lds + 48 * WSTR;                      // [8][7][192]
    float* g_lds = lds + 48 * WSTR + 8 * NBUF * CBUF_DW; // [48][16]

    const int wg   = blockIdx.x;
    const int cg   = wg % CG;
    const int sg   = wg / CG;
    const int tid  = threadIdx.x;
    const int w    = tid >> 6;
    const int lane = tid & 63;
    const int rt   = lane >> 2;          // row-tile: rows 3rt..3rt+2
    const int bt   = lane & 3;           // batch-tile: batches 4bt..4bt+3
    const int b0   = sg * BW;
    const int nst  = (25 * w) >> 2;      // wave's chunk range [nst, nen)
    const int nen  = (25 * (w + 1)) >> 2;
    const int nch  = nen - nst;          // 6 or 7
    const int sb   = lane / 3, sj = lane - 3 * sb;   // staging map (lane<48)
    float* mycbuf  = cbuf + w * NBUF * CBUF_DW;

    // ---- one-time: stage W_hh slice into LDS [48][612] ----
    for (int i4 = tid; i4 < 48 * 150; i4 += BLOCK) {
        int r = i4 / 150, col = i4 - r * 150;
        int gg = r / 12, cc = r - gg * 12;
        *(float4*)&W_lds[r * WSTR + 4 * col] =
            *(const float4*)(W_hh + ((size_t)(gg * HH + cg * CPW + cc)) * HH + 4 * col);
    }

    // ---- pointwise constants (tid<192: cell=cg*12+(tid>>4), batch=tid&15) ----
    const int pc = tid >> 4, pb = tid & 15;
    const int cell = cg * CPW + pc;
    const int bglob = b0 + pb;
    float wihv[4], biasv[4], cst = 0.f;
    if (tid < 192) {
        #pragma unroll
        for (int g = 0; g < 4; ++g) {
            const int grow = g * HH + cell;
            wihv[g]  = W_ih[grow];
            biasv[g] = b_ih[grow] + b_hh[grow];
        }
        cst = cs0[(size_t)bglob * HH + cell];
    }

    unsigned int* myflag = &flags[wg * 16];
    // parallel poll: lane l (l<nch) watches producer nst+l of this batch-group
    const unsigned int* pollp =
        &flags[(sg * CG + nst + ((lane < nch) ? lane : 0)) * 16];
    const bool mine = (lane < nch);

    for (int t = 0; t < TT; ++t) {
        // [A] zero gate accumulator
        if (tid < 192) *(float4*)&g_lds[4 * tid] = make_float4(0.f, 0.f, 0.f, 0.f);
        __syncthreads();                                   // [B]

        // [C] per-wave: poll own producers (parallel, one ballot loop)
        if (t > 0) {
            const unsigned thr3 = 3u * (unsigned)t;
            for (;;) {
                unsigned fv = __hip_atomic_load(pollp, __ATOMIC_RELAXED,
                                                __HIP_MEMORY_SCOPE_AGENT);
                if (__all(!mine || fv >= thr3)) break;
                __builtin_amdgcn_s_sleep(1);
            }
        }
        const float* hsrc = (t == 0) ? hs0 : (hbuf + (size_t)(t & 1) * BB * HH);
        // issue ALL chunk stages back-to-back (overlapping IF$ RTs)
        for (int i = 0; i < nch; ++i) {
            if (lane < 48) {
                const float* gp = hsrc + (size_t)(b0 + sb) * HH
                                       + 12 * (nst + i) + 4 * sj;
                __builtin_amdgcn_global_load_lds(gp, (void*)(mycbuf + i * CBUF_DW),
                                                 16, 0, 17 /* sc0|sc1 */);
            }
        }
        f2v acc2[3][4];
        #pragma unroll
        for (int ii = 0; ii < 3; ++ii)
            #pragma unroll
            for (int jj = 0; jj < 4; ++jj)
                acc2[ii][jj] = (f2v){0.f, 0.f};
        if (nch == 7) process_chunks<7>(W_lds, mycbuf, nst, rt, bt, acc2);
        else          process_chunks<6>(W_lds, mycbuf, nst, rt, bt, acc2);

        // cross-wave reduce: 12 LDS f32 atomic adds per lane, once per step
        #pragma unroll
        for (int ii = 0; ii < 3; ++ii)
            #pragma unroll
            for (int jj = 0; jj < 4; ++jj)
                atomicAdd(&g_lds[(3 * rt + ii) * 16 + 4 * bt + jj],
                          acc2[ii][jj][0] + acc2[ii][jj][1]);
        __syncthreads();                                   // [D]

        // [E] pointwise (waves 0-2), publish h, per-wave drained flag add
        if (tid < 192) {
            const float xv = x[(size_t)bglob * TT + t];
            const float gi  = g_lds[(0 * CPW + pc) * 16 + pb] + xv * wihv[0] + biasv[0];
            const float gf  = g_lds[(1 * CPW + pc) * 16 + pb] + xv * wihv[1] + biasv[1];
            const float gg_ = g_lds[(2 * CPW + pc) * 16 + pb] + xv * wihv[2] + biasv[2];
            const float go  = g_lds[(3 * CPW + pc) * 16 + pb] + xv * wihv[3] + biasv[3];
            const float cn = sigm_f(gf) * cst + sigm_f(gi) * tanh_f(gg_);
            cst = cn;
            const float hv = sigm_f(go) * tanh_f(cn);
            stg_bypass(hbuf + (size_t)((t + 1) & 1) * BB * HH
                            + (size_t)bglob * HH + cell, hv);
            asm volatile("s_waitcnt vmcnt(0)" ::: "memory");  // own wave's h in IF$
            if (lane == 0) atomicAdd(myflag, 1u);             // +3 total per step
        }
        __syncthreads();                                   // [F]
    }
}

// final projection: out[b,o] = h_T[b,:] @ W_out[o,:] + b_out[o]
extern "C" __global__ void lstm_out(const float* __restrict__ hbuf0,
                                    const float* __restrict__ W_out,
                                    const float* __restrict__ b_out,
                                    float* __restrict__ out)
{
    int b = blockIdx.x;
    int lane = threadIdx.x;
    float acc[10] = {};
    for (int k = lane; k < HH; k += 64) {
        float hv = hbuf0[(size_t)b * HH + k];
        #pragma unroll
        for (int o = 0; o < 10; ++o)
            acc[o] += hv * W_out[(size_t)o * HH + k];
    }
    #pragma unroll
    for (int o = 0; o < 10; ++o) {
        float v = acc[o];
        for (int off = 32; off > 0; off >>= 1) v += __shfl_down(v, off);
        if (lane == 0) out[b * 10 + o] = v + b_out[o];
    }
}

extern "C" void kernel_launch(void* const* d_in, const int* in_sizes, int n_in,
                              void* d_out, int out_size, void* d_ws, size_t ws_size,
                              hipStream_t stream)
{
    const float* x     = (const float*)d_in[0];
    const float* hs0   = (const float*)d_in[1];
    const float* cs0   = (const float*)d_in[2];
    const float* W_ih  = (const float*)d_in[3];
    const float* W_hh  = (const float*)d_in[4];
    const float* b_ih  = (const float*)d_in[5];
    const float* b_hh  = (const float*)d_in[6];
    const float* W_out = (const float*)d_in[7];
    const float* b_out = (const float*)d_in[8];
    float* out = (float*)d_out;

    // workspace: hbuf[2][64][600] f32, then flags[200] spaced 64 B
    float* hbuf = (float*)d_ws;
    unsigned int* flags = (unsigned int*)((char*)d_ws + (size_t)2 * BB * HH * sizeof(float));

    hipFuncSetAttribute((const void*)lstm_main,
                        hipFuncAttributeMaxDynamicSharedMemorySize, LDS_BYTES);

    hipMemsetAsync(flags, 0, NWG * 16 * sizeof(unsigned int), stream);
    hipLaunchKernelGGL(lstm_main, dim3(NWG), dim3(BLOCK), LDS_BYTES, stream,
                       x, hs0, cs0, W_ih, W_hh, b_ih, b_hh, hbuf, flags);
    // t=783 writes hbuf[(784)&1] = hbuf[0]
    hipLaunchKernelGGL(lstm_out, dim3(BB), dim3(64), 0, stream,
                       hbuf, W_out, b_out, out);
}

// Round 13
// 5413.151 us; speedup vs baseline: 1.9662x; 1.9662x over previous
//
#include <hip/hip_runtime.h>
#include <math.h>

// LSTM: B=64, T=784, I=1, H=600.
// r4 base (proven 4.3ms: 50 cell-groups x 4 batch-groups, 12 cells x 16
// batches/WG, sc0sc1 IF$ exchange, relaxed-agent flags) with ROLE-SPLIT waves:
//   waves 0-2: GEMV rows 0-17 + pointwise + publish (+3 drained flag adds)
//   waves 3-7: GEMV rows 18-47 + per-producer fused poll+stage of h(t+1)
//              into the alternate LDS h buffer (overlaps peers' pointwise).
// Intra-WG sync: 1 barrier/step + LDS gather-counter spin (was 4 barriers).
#define BB 64
#define TT 784
#define HH 600
#define CG 50           // cell-groups == producers per batch-group
#define CPW 12          // cells per WG -> 48 gate-rows
#define BW 16           // batches per WG
#define NWG (CG*4)      // 200
#define BLOCK 512       // 8 waves; wave owns 6 gate-rows; lane=(bh:2 x kh:32)
#define HB4 (BW*150)    // 2400 float4 of h per buffer
#define HBUF_DW 9600    // dwords per h buffer
#define LDS_BYTES (84*1024)   // force 1 WG/CU (actual use ~80KB)

typedef float f4v __attribute__((ext_vector_type(4)));

__device__ __forceinline__ float dot4acc(f4v a, float4 b, float acc) {
    acc = fmaf(a[0], b.x, acc);
    acc = fmaf(a[1], b.y, acc);
    acc = fmaf(a[2], b.z, acc);
    acc = fmaf(a[3], b.w, acc);
    return acc;
}

// five pipelined cache-bypassing 16B loads (one IF$ latency) -- t=0 staging
__device__ __forceinline__ void ldg5_bypass(const float4* g0, const float4* g1,
                                            const float4* g2, const float4* g3,
                                            const float4* g4,
                                            float4& a, float4& b, float4& c,
                                            float4& d, float4& e) {
    asm volatile(
        "global_load_dwordx4 %0, %5, off sc0 sc1\n\t"
        "global_load_dwordx4 %1, %6, off sc0 sc1\n\t"
        "global_load_dwordx4 %2, %7, off sc0 sc1\n\t"
        "global_load_dwordx4 %3, %8, off sc0 sc1\n\t"
        "global_load_dwordx4 %4, %9, off sc0 sc1\n\t"
        "s_waitcnt vmcnt(0)"
        : "=&v"(a), "=&v"(b), "=&v"(c), "=&v"(d), "=&v"(e)
        : "v"(g0), "v"(g1), "v"(g2), "v"(g3), "v"(g4)
        : "memory");
}

__device__ __forceinline__ void ldg4_nw(const float4* g0, const float4* g1,
                                        const float4* g2, const float4* g3,
                                        float4& A, float4& B, float4& C, float4& D) {
    asm volatile(
        "global_load_dwordx4 %0, %4, off sc0 sc1\n\t"
        "global_load_dwordx4 %1, %5, off sc0 sc1\n\t"
        "global_load_dwordx4 %2, %6, off sc0 sc1\n\t"
        "global_load_dwordx4 %3, %7, off sc0 sc1"
        : "=&v"(A), "=&v"(B), "=&v"(C), "=&v"(D)
        : "v"(g0), "v"(g1), "v"(g2), "v"(g3) : "memory");
}

__device__ __forceinline__ void ldg4_w(const float4* g0, const float4* g1,
                                       const float4* g2, const float4* g3,
                                       float4& A, float4& B, float4& C, float4& D) {
    asm volatile(
        "global_load_dwordx4 %0, %4, off sc0 sc1\n\t"
        "global_load_dwordx4 %1, %5, off sc0 sc1\n\t"
        "global_load_dwordx4 %2, %6, off sc0 sc1\n\t"
        "global_load_dwordx4 %3, %7, off sc0 sc1\n\t"
        "s_waitcnt vmcnt(0)"
        : "=&v"(A), "=&v"(B), "=&v"(C), "=&v"(D)
        : "v"(g0), "v"(g1), "v"(g2), "v"(g3) : "memory");
}

__device__ __forceinline__ void stg_bypass(float* p, float v) {
    asm volatile("global_store_dword %0, %1, off sc0 sc1"
                 :: "v"(p), "v"(v) : "memory");
}

__device__ __forceinline__ float sigm_f(float v) {
    return 1.f / (1.f + __expf(-v));
}
__device__ __forceinline__ float tanh_f(float v) {
    return 1.f - 2.f / (__expf(2.f * v) + 1.f);
}

// fold CNT*2 partial sums down to CNT across lane-pairs (kh ^ MASK).
template<int MASK, int CNT>
__device__ __forceinline__ void fold(float* v, int kh) {
    const bool hi = (kh & MASK) != 0;
    #pragma unroll
    for (int i = 0; i < CNT; ++i) {
        float send = hi ? v[i] : v[i + CNT];
        float recv = __shfl_xor(send, MASK);
        v[i] = (hi ? v[i + CNT] : v[i]) + recv;
    }
}

extern "C" __global__ void __launch_bounds__(BLOCK, 2)
lstm_main(const float* __restrict__ x, const float* __restrict__ hs0,
          const float* __restrict__ cs0, const float* __restrict__ W_ih,
          const float* __restrict__ W_hh, const float* __restrict__ b_ih,
          const float* __restrict__ b_hh, float* __restrict__ hbuf,
          unsigned int* __restrict__ flags)
{
    extern __shared__ float lds[];
    // h double buffer: [2][16 b][150 f4], linear f4 layout (r4-identical)
    float* g_lds = lds + 2 * HBUF_DW;            // [48 rows][16 b]
    unsigned* ctr = (unsigned*)(lds + 2 * HBUF_DW + 48 * 16);

    const int wg   = blockIdx.x;
    const int cg   = wg % CG;             // cell-group
    const int sg   = wg / CG;             // batch-group
    const int tid  = threadIdx.x;
    const int w    = tid >> 6;            // wave 0..7
    const int lane = tid & 63;
    const int bh   = lane >> 5;           // batch half
    const int kh   = lane & 31;           // k-chunk id (20 floats)
    const int khc  = (kh < 30) ? kh : 29;
    const int b0   = sg * BW;

    // ---- one-time: W_hh rows 6w..6w+5, k-chunk khc*20..+19 (r4 exact) ----
    f4v Wr[6][5];
    #pragma unroll
    for (int r = 0; r < 6; ++r) {
        const int row = 6 * w + r;
        const int g   = row / 12, c = row % 12;
        const float* wrow = W_hh + ((size_t)g * HH + cg * CPW + c) * HH + khc * 20;
        #pragma unroll
        for (int j = 0; j < 5; ++j) {
            f4v z = {0.f, 0.f, 0.f, 0.f};
            Wr[r][j] = (kh < 30) ? *(const f4v*)(wrow + 4 * j) : z;
        }
    }

    // ---- pointwise-lane constants (tid<192: cell=cg*12+(tid>>4), b=tid&15) ----
    float wihv[4], biasv[4], cst = 0.f;
    const int pc = tid >> 4, pb = tid & 15;
    const int cell = cg * CPW + pc;
    const int bglob = b0 + pb;
    if (tid < 192) {
        #pragma unroll
        for (int g = 0; g < 4; ++g) {
            const int grow = g * HH + cell;
            wihv[g]  = W_ih[grow];
            biasv[g] = b_ih[grow] + b_hh[grow];
        }
        cst = cs0[(size_t)bglob * HH + cell];
    }

    // ---- stager constants (waves 3-7, 6 lanes per producer) ----
    const int swl = w - 3;                       // 0..4
    const int sp  = (w >= 3 && lane < 60) ? (10 * swl + lane / 6) : -1;
    const int ss  = lane % 6;                    // sub-slot: f4 j = 8ss..8ss+7
    const bool sact = (sp >= 0 && sp != cg);
    const unsigned int* spflag = &flags[(sg * CG + (sact ? sp : 0)) * 16];
    int soff[8], ldo[8];
    if (sact) {
        #pragma unroll
        for (int jj = 0; jj < 8; ++jj) {
            const int j = 8 * ss + jj, bj = j / 3, cj = j - 3 * bj;
            soff[jj] = (b0 + bj) * HH + CPW * sp + 4 * cj;   // global dwords
            ldo[jj]  = bj * HH + CPW * sp + 4 * cj;          // LDS dwords
        }
    }

    // ---- prologue: ctr=0; stage hs0 into h buffer 0 (r4 ldg5 pattern) ----
    if (tid == 0) *ctr = 0u;
    {
        const int i0 = tid, i1 = tid + 512, i2 = tid + 1024, i3 = tid + 1536;
        const int i4 = (tid + 2048 < HB4) ? tid + 2048 : HB4 - 1;
        const float4* s4 = (const float4*)hs0 + (size_t)b0 * 150;
        float4 v0, v1, v2, v3, v4;
        ldg5_bypass(s4 + i0, s4 + i1, s4 + i2, s4 + i3, s4 + i4,
                    v0, v1, v2, v3, v4);
        float4* h0 = (float4*)lds;
        h0[i0] = v0; h0[i1] = v1; h0[i2] = v2; h0[i3] = v3; h0[i4] = v4;
    }
    __syncthreads();

    unsigned int* myflag = &flags[wg * 16];

    for (int t = 0; t < TT; ++t) {
        const int P = t & 1;
        float xv = 0.f;
        if (tid < 192) xv = x[(size_t)bglob * TT + t];

        // ---- GEMV from h[P] (r4 exact: b128 reads, zero-conflict) ----
        float v[48];
        {
            float acc[48];
            #pragma unroll
            for (int i = 0; i < 48; ++i) acc[i] = 0.f;
            const float4* hb_base = (const float4*)(lds + P * HBUF_DW)
                                    + (size_t)bh * 8 * 150 + khc * 5;
            #pragma unroll
            for (int bi = 0; bi < 8; ++bi) {
                const float4* hb = hb_base + bi * 150;
                const float4 h0 = hb[0], h1 = hb[1], h2 = hb[2],
                             h3 = hb[3], hv4 = hb[4];
                #pragma unroll
                for (int r = 0; r < 6; ++r) {
                    float a = acc[r * 8 + bi];
                    a = dot4acc(Wr[r][0], h0, a);
                    a = dot4acc(Wr[r][1], h1, a);
                    a = dot4acc(Wr[r][2], h2, a);
                    a = dot4acc(Wr[r][3], h3, a);
                    a = dot4acc(Wr[r][4], hv4, a);
                    acc[r * 8 + bi] = a;
                }
            }
            #pragma unroll
            for (int i = 0; i < 48; ++i) v[i] = acc[i];
        }

        // ---- fold over 32 kh-lanes: 48 -> 24 -> 12 -> 6 -> 3 (r4 exact) ----
        fold<16, 24>(v, kh);
        fold<8, 12>(v, kh);
        fold<4, 6>(v, kh);
        fold<2, 3>(v, kh);
        #pragma unroll
        for (int i = 0; i < 3; ++i)
            v[i] += __shfl_xor(v[i], 1);

        // ---- gather (r4 exact) + LDS release: ctr += 1 per wave ----
        if (!(kh & 1)) {
            const int vb = 3 * (kh >> 1);
            #pragma unroll
            for (int s = 0; s < 3; ++s) {
                const int val = vb + s;
                const int rowl = val >> 3, bi = val & 7;
                g_lds[(6 * w + rowl) * 16 + bh * 8 + bi] = v[s];
            }
        }
        asm volatile("s_waitcnt lgkmcnt(0)" ::: "memory");
        if (lane == 0) atomicAdd(ctr, 1u);

        if (w >= 3) {
            // ---- stager path: fused poll + stage h(t+1) into h[P^1] ----
            if (sact && t < TT - 1) {
                const unsigned thr = 3u * (unsigned)(t + 1);
                while (__hip_atomic_load(spflag, __ATOMIC_RELAXED,
                                         __HIP_MEMORY_SCOPE_AGENT) < thr)
                    __builtin_amdgcn_s_sleep(1);
                const float* hb1 = hbuf + (size_t)((t + 1) & 1) * BB * HH;
                float4 d0, d1, d2, d3, d4, d5, d6, d7;
                ldg4_nw((const float4*)(hb1 + soff[0]), (const float4*)(hb1 + soff[1]),
                        (const float4*)(hb1 + soff[2]), (const float4*)(hb1 + soff[3]),
                        d0, d1, d2, d3);
                ldg4_w((const float4*)(hb1 + soff[4]), (const float4*)(hb1 + soff[5]),
                       (const float4*)(hb1 + soff[6]), (const float4*)(hb1 + soff[7]),
                       d4, d5, d6, d7);
                __builtin_amdgcn_sched_barrier(0);
                float* hn = lds + (P ^ 1) * HBUF_DW;
                *(float4*)&hn[ldo[0]] = d0; *(float4*)&hn[ldo[1]] = d1;
                *(float4*)&hn[ldo[2]] = d2; *(float4*)&hn[ldo[3]] = d3;
                *(float4*)&hn[ldo[4]] = d4; *(float4*)&hn[ldo[5]] = d5;
                *(float4*)&hn[ldo[6]] = d6; *(float4*)&hn[ldo[7]] = d7;
            }
        } else {
            // ---- compute path: spin for gather, pointwise, publish ----
            const unsigned ct = 8u * (unsigned)(t + 1);
            while (__hip_atomic_load(ctr, __ATOMIC_RELAXED,
                                     __HIP_MEMORY_SCOPE_WORKGROUP) < ct) {}
            const float gi  = g_lds[(0 * 12 + pc) * 16 + pb] + xv * wihv[0] + biasv[0];
            const float gf  = g_lds[(1 * 12 + pc) * 16 + pb] + xv * wihv[1] + biasv[1];
            const float gg_ = g_lds[(2 * 12 + pc) * 16 + pb] + xv * wihv[2] + biasv[2];
            const float go  = g_lds[(3 * 12 + pc) * 16 + pb] + xv * wihv[3] + biasv[3];
            const float cn = sigm_f(gf) * cst + sigm_f(gi) * tanh_f(gg_);
            cst = cn;
            const float hv = sigm_f(go) * tanh_f(cn);
            // own slice directly into next LDS h buffer (no global RT)
            lds[(P ^ 1) * HBUF_DW + pb * HH + cell - b0 * 0 * HH - 0] = 0.f; // placeholder overwritten below
            lds[(P ^ 1) * HBUF_DW + pb * HH + cg * CPW + pc] = hv;
            // publish for peers + per-wave drained flag add
            stg_bypass(hbuf + (size_t)((t + 1) & 1) * BB * HH
                            + (size_t)bglob * HH + cell, hv);
            asm volatile("s_waitcnt vmcnt(0)" ::: "memory");
            if (lane == 0) atomicAdd(myflag, 1u);
        }
        __syncthreads();
    }
}

// final projection: out[b,o] = h_T[b,:] @ W_out[o,:] + b_out[o]
extern "C" __global__ void lstm_out(const float* __restrict__ hbuf0,
                                    const float* __restrict__ W_out,
                                    const float* __restrict__ b_out,
                                    float* __restrict__ out)
{
    int b = blockIdx.x;
    int lane = threadIdx.x;
    float acc[10] = {};
    for (int k = lane; k < HH; k += 64) {
        float hv = hbuf0[(size_t)b * HH + k];
        #pragma unroll
        for (int o = 0; o < 10; ++o)
            acc[o] += hv * W_out[(size_t)o * HH + k];
    }
    #pragma unroll
    for (int o = 0; o < 10; ++o) {
        float v = acc[o];
        for (int off = 32; off > 0; off >>= 1) v += __shfl_down(v, off);
        if (lane == 0) out[b * 10 + o] = v + b_out[o];
    }
}

extern "C" void kernel_launch(void* const* d_in, const int* in_sizes, int n_in,
                              void* d_out, int out_size, void* d_ws, size_t ws_size,
                              hipStream_t stream)
{
    const float* x     = (const float*)d_in[0];
    const float* hs0   = (const float*)d_in[1];
    const float* cs0   = (const float*)d_in[2];
    const float* W_ih  = (const float*)d_in[3];
    const float* W_hh  = (const float*)d_in[4];
    const float* b_ih  = (const float*)d_in[5];
    const float* b_hh  = (const float*)d_in[6];
    const float* W_out = (const float*)d_in[7];
    const float* b_out = (const float*)d_in[8];
    float* out = (float*)d_out;

    // workspace: hbuf[2][64][600] f32, then flags[200] spaced 64 B
    float* hbuf = (float*)d_ws;
    unsigned int* flags = (unsigned int*)((char*)d_ws + (size_t)2 * BB * HH * sizeof(float));

    hipFuncSetAttribute((const void*)lstm_main,
                        hipFuncAttributeMaxDynamicSharedMemorySize, LDS_BYTES);

    hipMemsetAsync(flags, 0, NWG * 16 * sizeof(unsigned int), stream);
    hipLaunchKernelGGL(lstm_main, dim3(NWG), dim3(BLOCK), LDS_BYTES, stream,
                       x, hs0, cs0, W_ih, W_hh, b_ih, b_hh, hbuf, flags);
    // t=783 writes hbuf[(784)&1] = hbuf[0]
    hipLaunchKernelGGL(lstm_out, dim3(BB), dim3(64), 0, stream,
                       hbuf, W_out, b_out, out);
}